// Round 1
// baseline (80.758 us; speedup 1.0000x reference)
//
#include <hip/hip_runtime.h>

// loss = (N*S - ||colsum||^2) / (sqrt(max_i sq_i) * N*(N-1)/2)
// where S = sum of all x^2, colsum[d] = sum_i x[i][d], sq_i = row squared norm.
// Derivation: sum_{i<j} (sq_i + sq_j - 2 x_i.x_j) = N*S - ||colsum||^2.

#define NROWS 8192
#define NCOLS 512

// ws layout: [0..511] column sums, [512] S, [513] max row sq (uint-as-float)

__global__ __launch_bounds__(256) void ndl_pass1(const float* __restrict__ x,
                                                 float* __restrict__ ws) {
    __shared__ float colsum[NCOLS];
    __shared__ float s_part[4];
    const int t    = threadIdx.x;
    const int lane = t & 63;
    const int wave = t >> 6;

    colsum[t]       = 0.f;
    colsum[t + 256] = 0.f;
    __syncthreads();

    // wave handles 8 consecutive rows; lane l covers columns 8l..8l+7
    const int row0 = blockIdx.x * 32 + wave * 8;
    const float4* xv = (const float4*)x;  // row stride = 128 float4

    float col[8] = {0.f, 0.f, 0.f, 0.f, 0.f, 0.f, 0.f, 0.f};
    float sp = 0.f;       // per-lane sum of squares
    float maxsq = 0.f;    // per-lane running max of row sq (post-butterfly, all lanes equal)

    #pragma unroll
    for (int r = 0; r < 8; ++r) {
        const int row = row0 + r;
        float4 a = xv[row * 128 + lane * 2];
        float4 b = xv[row * 128 + lane * 2 + 1];
        col[0] += a.x; col[1] += a.y; col[2] += a.z; col[3] += a.w;
        col[4] += b.x; col[5] += b.y; col[6] += b.z; col[7] += b.w;
        float rsq = a.x*a.x + a.y*a.y + a.z*a.z + a.w*a.w
                  + b.x*b.x + b.y*b.y + b.z*b.z + b.w*b.w;
        sp += rsq;
        // butterfly: all lanes end with full row sq
        #pragma unroll
        for (int off = 1; off < 64; off <<= 1)
            rsq += __shfl_xor(rsq, off, 64);
        maxsq = fmaxf(maxsq, rsq);
    }

    // per-lane column partials -> LDS (4-way contention across waves, cheap)
    const int base = lane * 8;
    #pragma unroll
    for (int k = 0; k < 8; ++k)
        atomicAdd(&colsum[base + k], col[k]);

    // S: wave reduce then block combine
    #pragma unroll
    for (int off = 1; off < 64; off <<= 1)
        sp += __shfl_xor(sp, off, 64);
    if (lane == 0) {
        s_part[wave] = sp;
        // sq >= 0 so uint bit-pattern compare is order-preserving
        atomicMax((unsigned int*)&ws[513], __float_as_uint(maxsq));
    }
    __syncthreads();

    if (t == 0)
        atomicAdd(&ws[512], s_part[0] + s_part[1] + s_part[2] + s_part[3]);

    atomicAdd(&ws[t],       colsum[t]);
    atomicAdd(&ws[t + 256], colsum[t + 256]);
}

__global__ __launch_bounds__(256) void ndl_pass2(const float* __restrict__ ws,
                                                 float* __restrict__ out) {
    __shared__ float red[4];
    const int t    = threadIdx.x;
    const int lane = t & 63;
    const int wave = t >> 6;

    float v0 = ws[t];
    float v1 = ws[t + 256];
    float ssq = v0 * v0 + v1 * v1;
    #pragma unroll
    for (int off = 1; off < 64; off <<= 1)
        ssq += __shfl_xor(ssq, off, 64);
    if (lane == 0) red[wave] = ssq;
    __syncthreads();

    if (t == 0) {
        double ss    = (double)red[0] + (double)red[1] + (double)red[2] + (double)red[3];
        double S     = (double)ws[512];
        double maxsq = (double)ws[513];
        double numer = (double)NROWS * S - ss;
        double count = (double)NROWS * ((double)NROWS - 1.0) * 0.5;
        out[0] = (float)(numer / (sqrt(maxsq) * count));
    }
}

extern "C" void kernel_launch(void* const* d_in, const int* in_sizes, int n_in,
                              void* d_out, int out_size, void* d_ws, size_t ws_size,
                              hipStream_t stream) {
    const float* x = (const float*)d_in[0];
    float* out = (float*)d_out;
    float* ws  = (float*)d_ws;

    hipMemsetAsync(ws, 0, 514 * sizeof(float), stream);
    ndl_pass1<<<NROWS / 32, 256, 0, stream>>>(x, ws);
    ndl_pass2<<<1, 256, 0, stream>>>(ws, out);
}

// Round 2
// 73.209 us; speedup vs baseline: 1.1031x; 1.1031x over previous
//
#include <hip/hip_runtime.h>

// loss = (N*S - ||colsum||^2) / (sqrt(max_i sq_i) * N*(N-1)/2)
// where S = sum of all x^2, colsum[d] = sum_i x[i][d], sq_i = row squared norm.
// Derivation: sum_{i<j} (sq_i + sq_j - 2 x_i.x_j) = N*S - ||colsum||^2.
//
// No global atomics: pass1 writes per-block partials (plain stores, no init
// needed -> no memset dispatch); pass2 (1 block) reduces them.

#define NROWS 8192
#define NCOLS 512
#define NB1   256                 // pass1 block count
#define PS    (NB1 * NCOLS)       // ws offset: per-block S partials [NB1]
#define PM    (PS + NB1)          // ws offset: per-block max-sq partials [NB1]

__global__ __launch_bounds__(256) void ndl_pass1(const float* __restrict__ x,
                                                 float* __restrict__ ws) {
    __shared__ float colsum[NCOLS];
    __shared__ float s_part[4];
    __shared__ float m_part[4];
    const int t    = threadIdx.x;
    const int lane = t & 63;
    const int wave = t >> 6;

    colsum[t]       = 0.f;
    colsum[t + 256] = 0.f;
    __syncthreads();

    // wave handles 8 consecutive rows; lane l covers columns 8l..8l+7
    const int row0 = blockIdx.x * 32 + wave * 8;
    const float4* xv = (const float4*)x;  // row stride = 128 float4

    float col[8] = {0.f, 0.f, 0.f, 0.f, 0.f, 0.f, 0.f, 0.f};
    float sp = 0.f;       // per-lane sum of squares
    float maxsq = 0.f;

    #pragma unroll
    for (int r = 0; r < 8; ++r) {
        const int row = row0 + r;
        float4 a = xv[row * 128 + lane * 2];
        float4 b = xv[row * 128 + lane * 2 + 1];
        col[0] += a.x; col[1] += a.y; col[2] += a.z; col[3] += a.w;
        col[4] += b.x; col[5] += b.y; col[6] += b.z; col[7] += b.w;
        float rsq = a.x*a.x + a.y*a.y + a.z*a.z + a.w*a.w
                  + b.x*b.x + b.y*b.y + b.z*b.z + b.w*b.w;
        sp += rsq;
        // butterfly: all lanes end with the full row sq
        #pragma unroll
        for (int off = 1; off < 64; off <<= 1)
            rsq += __shfl_xor(rsq, off, 64);
        maxsq = fmaxf(maxsq, rsq);
    }

    // per-lane column partials -> LDS (4-way wave contention, LDS atomics: cheap)
    const int base = lane * 8;
    #pragma unroll
    for (int k = 0; k < 8; ++k)
        atomicAdd(&colsum[base + k], col[k]);

    #pragma unroll
    for (int off = 1; off < 64; off <<= 1)
        sp += __shfl_xor(sp, off, 64);
    if (lane == 0) { s_part[wave] = sp; m_part[wave] = maxsq; }
    __syncthreads();

    // plain stores of per-block partials — no global atomics, no pre-zero
    float* o = ws + (size_t)blockIdx.x * NCOLS;
    o[t]       = colsum[t];
    o[t + 256] = colsum[t + 256];
    if (t == 0) {
        ws[PS + blockIdx.x] = s_part[0] + s_part[1] + s_part[2] + s_part[3];
        ws[PM + blockIdx.x] = fmaxf(fmaxf(m_part[0], m_part[1]),
                                    fmaxf(m_part[2], m_part[3]));
    }
}

__global__ __launch_bounds__(1024) void ndl_pass2(const float* __restrict__ ws,
                                                  float* __restrict__ out) {
    __shared__ float cs[1024];
    __shared__ float red_q[16];
    __shared__ float red_s[16];
    __shared__ float red_m[16];
    const int t    = threadIdx.x;
    const int lane = t & 63;
    const int wave = t >> 6;
    const int col  = t & 511;
    const int half = t >> 9;     // 0 or 1: which 128-block slice to sum

    // column-reduce the 256 per-block partials; consecutive t -> consecutive
    // addresses for each fixed b (coalesced)
    const float* p = ws + (size_t)(half * 128) * NCOLS + col;
    float acc = 0.f;
    #pragma unroll 8
    for (int i = 0; i < 128; ++i)
        acc += p[(size_t)i * NCOLS];
    cs[t] = acc;
    __syncthreads();

    float qv = 0.f;                           // ||colsum||^2 contribution
    if (t < 512) {
        float c = cs[t] + cs[t + 512];
        qv = c * c;
    }
    float sv = (t < NB1) ? ws[PS + t] : 0.f;  // S contribution
    float mv = (t < NB1) ? ws[PM + t] : 0.f;  // max contribution (>=0)

    #pragma unroll
    for (int off = 1; off < 64; off <<= 1) {
        qv += __shfl_xor(qv, off, 64);
        sv += __shfl_xor(sv, off, 64);
        mv  = fmaxf(mv, __shfl_xor(mv, off, 64));
    }
    if (lane == 0) { red_q[wave] = qv; red_s[wave] = sv; red_m[wave] = mv; }
    __syncthreads();

    if (t == 0) {
        double ss = 0.0, S = 0.0;
        float  mx = 0.f;
        #pragma unroll
        for (int w = 0; w < 16; ++w) {
            ss += (double)red_q[w];
            S  += (double)red_s[w];
            mx  = fmaxf(mx, red_m[w]);
        }
        double numer = (double)NROWS * S - ss;
        double count = (double)NROWS * ((double)NROWS - 1.0) * 0.5;
        out[0] = (float)(numer / (sqrt((double)mx) * count));
    }
}

extern "C" void kernel_launch(void* const* d_in, const int* in_sizes, int n_in,
                              void* d_out, int out_size, void* d_ws, size_t ws_size,
                              hipStream_t stream) {
    const float* x = (const float*)d_in[0];
    float* out = (float*)d_out;
    float* ws  = (float*)d_ws;

    ndl_pass1<<<NB1, 256, 0, stream>>>(x, ws);
    ndl_pass2<<<1, 1024, 0, stream>>>(ws, out);
}

// Round 3
// 68.010 us; speedup vs baseline: 1.1874x; 1.0764x over previous
//
#include <hip/hip_runtime.h>

// loss = (N*S - ||colsum||^2) / (sqrt(max_i sq_i) * N*(N-1)/2)
// where S = sum of all x^2, colsum[d] = sum_i x[i][d], sq_i = row squared norm.
// Derivation: sum_{i<j} (sq_i + sq_j - 2 x_i.x_j) = N*S - ||colsum||^2.
//
// 3-stage, no global atomics:
//   pass1  (256 blocks): per-block colsum[512]/S/max partials, plain stores.
//   pass2a ( 64 blocks): block j fully reduces cols [8j,8j+8) over the 256
//                        block-partials -> sum of squares partial; also
//                        reduces a 4-wide slice of S/max partials.
//   pass2b (  1 block ): reduces 64+64+64 floats, emits the scalar.

#define NROWS 8192
#define NCOLS 512
#define NB1   256                 // pass1 block count
#define NB2   64                  // pass2a block count
#define PS    (NB1 * NCOLS)       // ws: S partials [NB1]
#define PM    (PS + NB1)          // ws: max partials [NB1]
#define PQ    (PM + NB1)          // ws: ssq stage-2 partials [NB2]
#define PS2   (PQ + NB2)          // ws: S stage-2 [NB2]
#define PM2   (PS2 + NB2)         // ws: max stage-2 [NB2]

__global__ __launch_bounds__(256) void ndl_pass1(const float* __restrict__ x,
                                                 float* __restrict__ ws) {
    __shared__ float colsum[NCOLS];
    __shared__ float s_part[4];
    __shared__ float m_part[4];
    const int t    = threadIdx.x;
    const int lane = t & 63;
    const int wave = t >> 6;

    colsum[t]       = 0.f;
    colsum[t + 256] = 0.f;
    __syncthreads();

    // wave handles 8 consecutive rows; lane l covers columns 8l..8l+7
    const int row0 = blockIdx.x * 32 + wave * 8;
    const float4* xv = (const float4*)x;  // row stride = 128 float4

    float col[8] = {0.f, 0.f, 0.f, 0.f, 0.f, 0.f, 0.f, 0.f};
    float sp = 0.f;
    float maxsq = 0.f;

    #pragma unroll
    for (int r = 0; r < 8; ++r) {
        const int row = row0 + r;
        float4 a = xv[row * 128 + lane * 2];
        float4 b = xv[row * 128 + lane * 2 + 1];
        col[0] += a.x; col[1] += a.y; col[2] += a.z; col[3] += a.w;
        col[4] += b.x; col[5] += b.y; col[6] += b.z; col[7] += b.w;
        float rsq = a.x*a.x + a.y*a.y + a.z*a.z + a.w*a.w
                  + b.x*b.x + b.y*b.y + b.z*b.z + b.w*b.w;
        sp += rsq;
        #pragma unroll
        for (int off = 1; off < 64; off <<= 1)
            rsq += __shfl_xor(rsq, off, 64);
        maxsq = fmaxf(maxsq, rsq);
    }

    const int base = lane * 8;
    #pragma unroll
    for (int k = 0; k < 8; ++k)
        atomicAdd(&colsum[base + k], col[k]);

    #pragma unroll
    for (int off = 1; off < 64; off <<= 1)
        sp += __shfl_xor(sp, off, 64);
    if (lane == 0) { s_part[wave] = sp; m_part[wave] = maxsq; }
    __syncthreads();

    float* o = ws + (size_t)blockIdx.x * NCOLS;
    o[t]       = colsum[t];
    o[t + 256] = colsum[t + 256];
    if (t == 0) {
        ws[PS + blockIdx.x] = s_part[0] + s_part[1] + s_part[2] + s_part[3];
        ws[PM + blockIdx.x] = fmaxf(fmaxf(m_part[0], m_part[1]),
                                    fmaxf(m_part[2], m_part[3]));
    }
}

// Block j: columns c = 8j..8j+7, fully summed over all 256 pass1 blocks.
// Thread t: c' = t&7, i = t>>3 (0..31); sums b = i*8+k, k=0..7.
__global__ __launch_bounds__(256) void ndl_pass2a(const float* __restrict__ ws_in,
                                                  float* __restrict__ ws) {
    __shared__ float wred[4 * 8];   // [wave][col'] per-wave column partials
    const int t    = threadIdx.x;
    const int lane = t & 63;
    const int wave = t >> 6;
    const int j    = blockIdx.x;
    const int c    = j * 8 + (t & 7);
    const int i    = t >> 3;

    const float* p = ws_in + (size_t)(i * 8) * NCOLS + c;
    float acc = 0.f;
    #pragma unroll
    for (int k = 0; k < 8; ++k)
        acc += p[(size_t)k * NCOLS];

    // sum over the 8 i-values within this wave (t bits 3,4,5)
    acc += __shfl_xor(acc, 8, 64);
    acc += __shfl_xor(acc, 16, 64);
    acc += __shfl_xor(acc, 32, 64);
    if (lane < 8) wred[wave * 8 + lane] = acc;
    __syncthreads();

    if (t < 8) {
        float cs = wred[t] + wred[8 + t] + wred[16 + t] + wred[24 + t];
        float q  = cs * cs;
        // sum the 8 squares (threads 0..7, same wave)
        q += __shfl_xor(q, 1, 64);
        q += __shfl_xor(q, 2, 64);
        q += __shfl_xor(q, 4, 64);
        if (t == 0) ws[PQ + j] = q;
    }
    if (t == 0) {
        float s = 0.f, m = 0.f;
        #pragma unroll
        for (int k = 0; k < 4; ++k) {
            s += ws_in[PS + j * 4 + k];
            m  = fmaxf(m, ws_in[PM + j * 4 + k]);
        }
        ws[PS2 + j] = s;
        ws[PM2 + j] = m;
    }
}

__global__ __launch_bounds__(64) void ndl_pass2b(const float* __restrict__ ws,
                                                 float* __restrict__ out) {
    const int t = threadIdx.x;
    float qv = ws[PQ + t];
    float sv = ws[PS2 + t];
    float mv = ws[PM2 + t];
    #pragma unroll
    for (int off = 1; off < 64; off <<= 1) {
        qv += __shfl_xor(qv, off, 64);
        sv += __shfl_xor(sv, off, 64);
        mv  = fmaxf(mv, __shfl_xor(mv, off, 64));
    }
    if (t == 0) {
        double numer = (double)NROWS * (double)sv - (double)qv;
        double count = (double)NROWS * ((double)NROWS - 1.0) * 0.5;
        out[0] = (float)(numer / (sqrt((double)mv) * count));
    }
}

extern "C" void kernel_launch(void* const* d_in, const int* in_sizes, int n_in,
                              void* d_out, int out_size, void* d_ws, size_t ws_size,
                              hipStream_t stream) {
    const float* x = (const float*)d_in[0];
    float* out = (float*)d_out;
    float* ws  = (float*)d_ws;

    ndl_pass1<<<NB1, 256, 0, stream>>>(x, ws);
    ndl_pass2a<<<NB2, 256, 0, stream>>>(ws, ws);
    ndl_pass2b<<<1, 64, 0, stream>>>(ws, out);
}